// Round 2
// baseline (173.041 us; speedup 1.0000x reference)
//
#include <hip/hip_runtime.h>
#include <hip/hip_bf16.h>

// Problem constants: B=2, T=2048, C=1024, H=16, D=64
#define BSZ 2
#define SEQ 2048
#define CDIM 1024
#define NHEAD 16
#define HDIM 64
#define M_GEMM (BSZ * SEQ)      // 4096
#define N_GEMM (3 * CDIM)       // 3072
#define K_GEMM CDIM             // 1024
#define QK_PITCH (2 * CDIM)     // 2048: qk buffer row pitch (Q|K only)

typedef __attribute__((ext_vector_type(8))) short short8;   // 8 bf16 = 16B
typedef __attribute__((ext_vector_type(4))) short short4v;  // 8B
typedef __attribute__((ext_vector_type(4))) float f32x4;

__device__ __forceinline__ short bf16_rn(float f) {
    unsigned u = __builtin_bit_cast(unsigned, f);
    u += 0x7FFF + ((u >> 16) & 1);          // round-to-nearest-even
    return (short)(u >> 16);
}

// async 16B global -> LDS (wave-uniform LDS base; HW adds lane*16)
__device__ __forceinline__ void gl2lds16(const short* g, short* l) {
    __builtin_amdgcn_global_load_lds(
        (const __attribute__((address_space(1))) unsigned int*)g,
        (__attribute__((address_space(3))) unsigned int*)l, 16, 0, 0);
}

// counted waits + raw barrier (NO vmcnt drain at barriers — that was the
// m97-structure stall). Memory clobbers pin LDS/global ops to their phase.
#define WAITV4() asm volatile("s_waitcnt vmcnt(4)" ::: "memory")
#define WAITV0() asm volatile("s_waitcnt vmcnt(0)" ::: "memory")
#define SBAR()                                  \
    do {                                        \
        asm volatile("" ::: "memory");          \
        __builtin_amdgcn_s_barrier();           \
        asm volatile("" ::: "memory");          \
    } while (0)

// ------------- Kernel 0: fused fp32->bf16 conversions ------------------------
// blocks [0, 2048): x -> xb (same layout). blocks [2048, 2816): W -> W^T tiles.
__global__ __launch_bounds__(256) void cvt_fused(const float* __restrict__ X,
                                                 const float* __restrict__ W,
                                                 short* __restrict__ Xb,
                                                 short* __restrict__ WT) {
    const int tid = threadIdx.x;
    if (blockIdx.x < 2048) {
        size_t idx = ((size_t)blockIdx.x * 256 + tid) * 8;
        float4 a = *(const float4*)&X[idx];
        float4 b = *(const float4*)&X[idx + 4];
        short8 o;
        o[0] = bf16_rn(a.x); o[1] = bf16_rn(a.y); o[2] = bf16_rn(a.z); o[3] = bf16_rn(a.w);
        o[4] = bf16_rn(b.x); o[5] = bf16_rn(b.y); o[6] = bf16_rn(b.z); o[7] = bf16_rn(b.w);
        *(short8*)&Xb[idx] = o;
        return;
    }
    __shared__ short T[64][72];
    const int bid = blockIdx.x - 2048;          // 0..767
    const int n0 = (bid % 48) * 64;
    const int k0 = (bid / 48) * 64;
#pragma unroll
    for (int pass = 0; pass < 4; ++pass) {
        int i = pass * 256 + tid;
        int kr = i >> 4;
        int n4 = i & 15;
        float4 v = *(const float4*)&W[(size_t)(k0 + kr) * N_GEMM + n0 + n4 * 4];
        T[n4 * 4 + 0][kr] = bf16_rn(v.x);
        T[n4 * 4 + 1][kr] = bf16_rn(v.y);
        T[n4 * 4 + 2][kr] = bf16_rn(v.z);
        T[n4 * 4 + 3][kr] = bf16_rn(v.w);
    }
    __syncthreads();
#pragma unroll
    for (int pass = 0; pass < 2; ++pass) {
        int o = pass * 256 + tid;
        int nr = o >> 3;
        int c8 = o & 7;
        *(short8*)&WT[(size_t)(n0 + nr) * K_GEMM + k0 + c8 * 8] =
            *(const short8*)&T[nr][c8 * 8];
    }
}

// -------- Kernel 1: qkv = x @ W + b — 256x256 tile, 8-wave, phase-interleaved
// R17 = R16 with STATIC 128 KiB LDS (dynamic-LDS + hipFuncSetAttribute was the
// prime crash suspect for the round-0 container failure; gfx950 static LDS
// limit is 160 KiB so 128 KiB static is legal, no host API involved).
//  - BM=BN=256, BK=64, 8 waves (2M x 4N), per-wave C = 128x64 (acc[8][4]).
//  - LDS: A[2][256][64] + B[2][256][64] bf16, chunk-XOR swizzled exactly like
//    the proven R14 kernel (LDS slot s of row r holds global chunk s^(r&7);
//    pre-swizzled global source, linear LDS dest for gl2lds).
//  - 4 phases per K-tile, one C-quadrant (16 MFMA) per phase, one stage unit
//    per phase into the OTHER buffer:  ph0:AE ph1:BE ph2:BO ph3:AO, where
//    AE/AO = A rows read in phases 0-1 / 2-3, BE/BO = B rows (mod 64) <32 / >=32.
//  - counted s_waitcnt vmcnt(4) ONLY at ends of phases 0,1,3 (never 0 in the
//    loop): 4 loads (2 units) always in flight across every barrier.
//    Ledger (steady state, per wave, issue order ... AE(t)BE(t)BO(t)AO(t)AE(t+1)...):
//      end ph3: out=8 -> vmcnt(4) drains AE,BE(t+1)  [read at t+1.ph0]
//      end ph0: out=6 -> vmcnt(4) drains BO(t)       [read at ph1]
//      end ph1: out=6 -> vmcnt(4) drains AO(t)       [read at ph2]
//      end ph2: nothing newly needed -> barrier only.
//  - raw s_barrier (no vmcnt drain); staging always targets buf^1 so there is
//    no same-buffer overwrite hazard; last iter stages a dummy tile 0 to keep
//    wait counts uniform, drained by vmcnt(0) after the loop.
__global__ __launch_bounds__(512, 2) void qkv_gemm_8ph(const short* __restrict__ A,
                                                       const short* __restrict__ Bt,
                                                       const float* __restrict__ bias,
                                                       short* __restrict__ Yqk,
                                                       short* __restrict__ Yv) {
    __shared__ short Asl[32768];   // [2][256][64] bf16 = 64 KiB
    __shared__ short Bsl[32768];   // [2][256][64] bf16 = 64 KiB

    const int tid  = threadIdx.x;
    const int w    = tid >> 6;        // wave 0..7
    const int lane = tid & 63;
    const int l16  = lane & 15;
    const int quad = lane >> 4;
    const int wm   = w >> 2;          // 0..1 (M)
    const int wn   = w & 3;           // 0..3 (N)
    const int ls   = lane >> 3;       // staging: row-in-slot 0..7
    const int lc   = lane & 7;        // staging: chunk 0..7
    const int fsw  = l16 & 7;         // frag-read swizzle

    // XCD-aware bijective swizzle: XCD x gets an 8(M) x 3(N) tile patch
    // (A panels 4MB + B panels 1.5MB ~ L2-resident per XCD). 192 % 8 == 0.
    const int orig = blockIdx.y * 12 + blockIdx.x;
    const int xcd  = orig & 7;
    const int idx  = orig >> 3;                      // 0..23
    const int bM   = ((xcd & 1) << 3) + (idx & 7);   // 0..15
    const int bN   = (xcd >> 1) * 3 + (idx >> 3);    // 0..11
    const int m0   = bM << 8;
    const int n0   = bN << 8;

    const short* Ab = A  + (size_t)m0 * K_GEMM;
    const short* Bb = Bt + (size_t)n0 * K_GEMM;

    f32x4 acc[8][4];
#pragma unroll
    for (int i = 0; i < 8; ++i)
#pragma unroll
        for (int j = 0; j < 4; ++j) acc[i][j] = (f32x4){0.f, 0.f, 0.f, 0.f};

    // stage one 128-row unit (16 KiB): 2 x gl2lds per thread. LDS dest is
    // wave-uniform and linear; the global source carries the XOR pre-swizzle.
    auto stageA = [&](int unit, int tt, int sbuf) {
#pragma unroll
        for (int i = 0; i < 2; ++i) {
            const int u0 = (i * 8 + w) * 8;                       // unit row base
            const int tr = (u0 & 63) + ((u0 >> 6) << 7) + unit * 64;
            gl2lds16(Ab + (size_t)(tr + ls) * K_GEMM + tt * 64 + ((lc ^ ls) << 3),
                     &Asl[sbuf * 16384 + tr * 64]);
        }
    };
    auto stageB = [&](int unit, int tt, int sbuf) {
#pragma unroll
        for (int i = 0; i < 2; ++i) {
            const int u0 = (i * 8 + w) * 8;
            const int tr = (u0 & 31) + ((u0 >> 5) << 6) + unit * 32;
            gl2lds16(Bb + (size_t)(tr + ls) * K_GEMM + tt * 64 + ((lc ^ ls) << 3),
                     &Bsl[sbuf * 16384 + tr * 64]);
        }
    };
    auto rdA = [&](int ab, int mi, int ks) -> short8 {
        const int r = wm * 128 + mi * 16 + l16;
        return *(const short8*)&Asl[ab + r * 64 + ((ks * 4 + quad) ^ fsw) * 8];
    };
    auto rdB = [&](int ab, int ni, int ks) -> short8 {
        const int r = wn * 64 + ni * 16 + l16;
        return *(const short8*)&Bsl[ab + r * 64 + ((ks * 4 + quad) ^ fsw) * 8];
    };

    // prologue: tile 0 -> buf 0, order AE,BE,BO,AO; keep BO,AO in flight.
    stageA(0, 0, 0);
    stageB(0, 0, 0);
    stageB(1, 0, 0);
    stageA(1, 0, 0);
    WAITV4();
    SBAR();

    for (int t = 0; t < 16; ++t) {
        const int buf = t & 1;
        const int sb  = buf ^ 1;
        const int tn  = (t + 1) & 15;     // t==15 stages dummy tile 0 (uniform waits)
        const int ab  = buf * 16384;

        short8 Af[4][2], Bf[2][2];

        // ---- phase 0: (miH0 x niH0); stage AE(t+1) ----
        stageA(0, tn, sb);
#pragma unroll
        for (int mi = 0; mi < 4; ++mi)
#pragma unroll
            for (int ks = 0; ks < 2; ++ks) Af[mi][ks] = rdA(ab, mi, ks);
#pragma unroll
        for (int ni = 0; ni < 2; ++ni)
#pragma unroll
            for (int ks = 0; ks < 2; ++ks) Bf[ni][ks] = rdB(ab, ni, ks);
        __builtin_amdgcn_s_setprio(1);
#pragma unroll
        for (int mi = 0; mi < 4; ++mi)
#pragma unroll
            for (int ni = 0; ni < 2; ++ni)
#pragma unroll
                for (int ks = 0; ks < 2; ++ks)
                    acc[mi][ni] = __builtin_amdgcn_mfma_f32_16x16x32_bf16(
                        Af[mi][ks], Bf[ni][ks], acc[mi][ni], 0, 0, 0);
        __builtin_amdgcn_s_setprio(0);
        WAITV4();
        SBAR();

        // ---- phase 1: (miH0 x niH1); stage BE(t+1); Af reused ----
        stageB(0, tn, sb);
#pragma unroll
        for (int ni = 0; ni < 2; ++ni)
#pragma unroll
            for (int ks = 0; ks < 2; ++ks) Bf[ni][ks] = rdB(ab, 2 + ni, ks);
        __builtin_amdgcn_s_setprio(1);
#pragma unroll
        for (int mi = 0; mi < 4; ++mi)
#pragma unroll
            for (int ni = 0; ni < 2; ++ni)
#pragma unroll
                for (int ks = 0; ks < 2; ++ks)
                    acc[mi][2 + ni] = __builtin_amdgcn_mfma_f32_16x16x32_bf16(
                        Af[mi][ks], Bf[ni][ks], acc[mi][2 + ni], 0, 0, 0);
        __builtin_amdgcn_s_setprio(0);
        WAITV4();
        SBAR();

        // ---- phase 2: (miH1 x niH0); stage BO(t+1); no vmcnt wait ----
        stageB(1, tn, sb);
#pragma unroll
        for (int mi = 0; mi < 4; ++mi)
#pragma unroll
            for (int ks = 0; ks < 2; ++ks) Af[mi][ks] = rdA(ab, 4 + mi, ks);
#pragma unroll
        for (int ni = 0; ni < 2; ++ni)
#pragma unroll
            for (int ks = 0; ks < 2; ++ks) Bf[ni][ks] = rdB(ab, ni, ks);
        __builtin_amdgcn_s_setprio(1);
#pragma unroll
        for (int mi = 0; mi < 4; ++mi)
#pragma unroll
            for (int ni = 0; ni < 2; ++ni)
#pragma unroll
                for (int ks = 0; ks < 2; ++ks)
                    acc[4 + mi][ni] = __builtin_amdgcn_mfma_f32_16x16x32_bf16(
                        Af[mi][ks], Bf[ni][ks], acc[4 + mi][ni], 0, 0, 0);
        __builtin_amdgcn_s_setprio(0);
        SBAR();

        // ---- phase 3: (miH1 x niH1); stage AO(t+1); Af reused ----
        stageA(1, tn, sb);
#pragma unroll
        for (int ni = 0; ni < 2; ++ni)
#pragma unroll
            for (int ks = 0; ks < 2; ++ks) Bf[ni][ks] = rdB(ab, 2 + ni, ks);
        __builtin_amdgcn_s_setprio(1);
#pragma unroll
        for (int mi = 0; mi < 4; ++mi)
#pragma unroll
            for (int ni = 0; ni < 2; ++ni)
#pragma unroll
                for (int ks = 0; ks < 2; ++ks)
                    acc[4 + mi][2 + ni] = __builtin_amdgcn_mfma_f32_16x16x32_bf16(
                        Af[mi][ks], Bf[ni][ks], acc[4 + mi][2 + ni], 0, 0, 0);
        __builtin_amdgcn_s_setprio(0);
        WAITV4();
        SBAR();
    }
    WAITV0();   // drain dummy loads: no LDS-DMA may outlive the workgroup

    // ---- epilogue ----
    if (n0 >= 2 * CDIM) {
        // V block: write transposed, 4 consecutive rows packed per 8B store
#pragma unroll
        for (int mi = 0; mi < 8; ++mi) {
            int row0 = m0 + wm * 128 + mi * 16 + quad * 4;
#pragma unroll
            for (int ni = 0; ni < 4; ++ni) {
                int colg = n0 + wn * 64 + ni * 16 + l16;
                float bb = bias[colg];
                short4v pk;
#pragma unroll
                for (int r = 0; r < 4; ++r) pk[r] = bf16_rn(acc[mi][ni][r] + bb);
                *(short4v*)&Yv[(size_t)(colg - 2 * CDIM) * M_GEMM + row0] = pk;
            }
        }
    } else {
        // Q pre-scale folds BOTH 1/sqrt(64) and log2(e): attn does p = 2^s
        const float qs = (n0 < CDIM) ? 0.125f * 1.44269504f : 1.0f;
#pragma unroll
        for (int mi = 0; mi < 8; ++mi)
#pragma unroll
            for (int r = 0; r < 4; ++r) {
                int row = m0 + wm * 128 + mi * 16 + quad * 4 + r;
#pragma unroll
                for (int ni = 0; ni < 4; ++ni) {
                    int colg = n0 + wn * 64 + ni * 16 + l16;
                    Yqk[(size_t)row * QK_PITCH + colg] =
                        bf16_rn((acc[mi][ni][r] + bias[colg]) * qs);
                }
            }
    }
}

// ---------- Kernel 2: causal flash attention, scrambled-qt coset balance -----
// R14 winner; softmax uses RAW v_exp_f32 via __builtin_amdgcn_exp2f. Q carries
// 0.125*log2e from the GEMM. 64 q-rows, 4 waves x 16; dbuf K/V, one
// barrier/tile; no-max softmax; XOR swizzle; wave-private Ps; coset-balanced
// qt mapping (constant 66 tile-iters/CU, bijective per band).
__global__ __launch_bounds__(256) void attn_mfma(const short* __restrict__ qk,
                                                 const short* __restrict__ vT,
                                                 float* __restrict__ out) {
    const int b = blockIdx.z;
    const int h = blockIdx.y;
    const int bx = blockIdx.x;           // 0..31
    const int u = h + 16 * b;            // 0..31
    const int band = u >> 3;             // 0..3
    const int base = (band & 2) ? ((bx + 16) & 31) : bx;
    const int qt = (band & 1) ? (31 - base) : base;
    const int tid = threadIdx.x;
    const int w = tid >> 6;
    const int lane = tid & 63;
    const int quad = lane >> 4;
    const int l16 = lane & 15;
    const int q0 = qt * 64;

    __shared__ short Ks[2][64 * 64];     // [buf][key][d], chunk-swizzled 16 KB
    __shared__ short Vt[2][64 * 64];     // [buf][d][key], chunk-swizzled 16 KB
    __shared__ short Ps[4 * 16 * 64];    // per-wave [q][key]              8 KB

    // staging descriptors: issue p covers chunks cid = p*256 + w*64 + lane
    int koff[2], voff[2], ldso[2];
#pragma unroll
    for (int p = 0; p < 2; ++p) {
        int cid = p * 256 + w * 64 + lane;
        int row = cid >> 3;
        int c = (cid & 7) ^ (row & 7);
        koff[p] = row * QK_PITCH + c * 8;
        voff[p] = row * M_GEMM + c * 8;
        ldso[p] = (p * 256 + w * 64) * 8;    // wave-uniform chunk base (shorts)
    }

    // Q fragments (A-layout: A[m=l16][k=quad*8+j])
    const short* qrow = qk + (size_t)(b * SEQ + q0 + w * 16 + l16) * QK_PITCH + h * HDIM;
    short8 aq[2];
    aq[0] = *(const short8*)(qrow + quad * 8);
    aq[1] = *(const short8*)(qrow + 32 + quad * 8);

    float l_run[4] = {0.f, 0.f, 0.f, 0.f};
    f32x4 o_acc[4];
#pragma unroll
    for (int dt = 0; dt < 4; ++dt) o_acc[dt] = (f32x4){0.f, 0.f, 0.f, 0.f};

    const int rowg0 = q0 + w * 16 + quad * 4;
    const short* kb0 = qk + (size_t)(b * SEQ) * QK_PITCH + CDIM + h * HDIM;
    const short* vb0 = vT + (size_t)(h * HDIM) * M_GEMM + b * SEQ;

    const int ksl = l16 & 7;
    short* PsW = &Ps[w * 1024];

    // prologue: stage tile 0 into buf 0
#pragma unroll
    for (int p = 0; p < 2; ++p) {
        gl2lds16(kb0 + koff[p], &Ks[0][ldso[p]]);
        gl2lds16(vb0 + voff[p], &Vt[0][ldso[p]]);
    }
    __syncthreads();                     // prologue staging drained

    for (int kt = 0; kt <= qt; ++kt) {
        const int cur = kt & 1;

        // prefetch tile kt+1 into the other buffer (overlaps compute)
        if (kt < qt) {
            const short* kbase = kb0 + (size_t)(kt + 1) * 64 * QK_PITCH;
            const short* vbase = vb0 + (kt + 1) * 64;
#pragma unroll
            for (int p = 0; p < 2; ++p) {
                gl2lds16(kbase + koff[p], &Ks[cur ^ 1][ldso[p]]);
                gl2lds16(vbase + voff[p], &Vt[cur ^ 1][ldso[p]]);
            }
        }

        const short* KsC = Ks[cur];
        const short* VtC = Vt[cur];

        // ---- QK^T: S[16 q][64 keys] (s already includes log2e factor) ----
        f32x4 s[4];
#pragma unroll
        for (int nt = 0; nt < 4; ++nt) s[nt] = (f32x4){0.f, 0.f, 0.f, 0.f};
#pragma unroll
        for (int nt = 0; nt < 4; ++nt)
#pragma unroll
            for (int ks = 0; ks < 2; ++ks) {
                short8 bk = *(const short8*)&KsC[(nt * 16 + l16) * 64 +
                                                 ((ks * 4 + quad) ^ ksl) * 8];
                s[nt] = __builtin_amdgcn_mfma_f32_16x16x32_bf16(aq[ks], bk, s[nt], 0, 0, 0);
            }

        // ---- no-max softmax: p = 2^s, ONE v_exp_f32 each; lane-local l ----
        if (kt < qt) {                   // full tile, wave-uniform
#pragma unroll
            for (int r = 0; r < 4; ++r) {
                const int qr = quad * 4 + r;
                float lsum = 0.f;
#pragma unroll
                for (int nt = 0; nt < 4; ++nt) {
                    float pp = __builtin_amdgcn_exp2f(s[nt][r]);
                    lsum += pp;
                    int slot = (nt * 2 + (l16 >> 3)) ^ (qr & 7);
                    PsW[qr * 64 + slot * 8 + (l16 & 7)] = bf16_rn(pp);
                }
                l_run[r] += lsum;
            }
        } else {                         // diagonal tile: causal mask
            const int keyb = kt * 64 + l16;
#pragma unroll
            for (int r = 0; r < 4; ++r) {
                const int qr = quad * 4 + r;
                const int rowg = rowg0 + r;
                float lsum = 0.f;
#pragma unroll
                for (int nt = 0; nt < 4; ++nt) {
                    float pp = __builtin_amdgcn_exp2f(s[nt][r]);
                    pp = ((keyb + nt * 16) > rowg) ? 0.f : pp;
                    lsum += pp;
                    int slot = (nt * 2 + (l16 >> 3)) ^ (qr & 7);
                    PsW[qr * 64 + slot * 8 + (l16 & 7)] = bf16_rn(pp);
                }
                l_run[r] += lsum;
            }
        }

        // ---- PV: O[16 q][64 d] += P @ V (Ps wave-private; no barrier) ----
#pragma unroll
        for (int dt = 0; dt < 4; ++dt)
#pragma unroll
            for (int ks = 0; ks < 2; ++ks) {
                short8 ap = *(const short8*)&PsW[l16 * 64 + ((ks * 4 + quad) ^ ksl) * 8];
                short8 bv = *(const short8*)&VtC[(dt * 16 + l16) * 64 +
                                                 ((ks * 4 + quad) ^ ksl) * 8];
                o_acc[dt] = __builtin_amdgcn_mfma_f32_16x16x32_bf16(ap, bv, o_acc[dt], 0, 0, 0);
            }

        // one barrier/tile: drains prefetch + guards buffer reuse
        __syncthreads();
    }

    // ---- epilogue: reduce l across the 16 key-lanes, normalize, store ----
#pragma unroll
    for (int r = 0; r < 4; ++r) {
        float l = l_run[r];
#pragma unroll
        for (int off = 1; off < 16; off <<= 1)
            l += __shfl_xor(l, off);
        float inv = 1.f / l;
        int row = q0 + w * 16 + quad * 4 + r;
        float* optr = out + (size_t)(b * SEQ + row) * CDIM + h * HDIM;
#pragma unroll
        for (int dt = 0; dt < 4; ++dt)
            optr[dt * 16 + l16] = o_acc[dt][r] * inv;
    }
}

// ------------------------------- launch --------------------------------------
extern "C" void kernel_launch(void* const* d_in, const int* in_sizes, int n_in,
                              void* d_out, int out_size, void* d_ws, size_t ws_size,
                              hipStream_t stream) {
    const float* x      = (const float*)d_in[0];   // [B,T,C] fp32
    const float* w_attn = (const float*)d_in[1];   // [C,3C]  fp32
    const float* b_attn = (const float*)d_in[2];   // [3C]    fp32
    float* out = (float*)d_out;                    // [B,T,C] fp32

    // workspace: qk [4096][2048] 16.78MB | vT [1024][4096] 8.39MB | xb 8.39MB | wT 6.29MB
    short* qk  = (short*)d_ws;
    short* vT  = (short*)((char*)d_ws + 16777216);
    short* xb  = (short*)((char*)d_ws + 25165824);
    short* wT  = (short*)((char*)d_ws + 33554432);

    cvt_fused<<<2048 + 768, 256, 0, stream>>>(x, w_attn, xb, wT);

    dim3 g1(N_GEMM / 256, M_GEMM / 256);                                // (12,16)
    qkv_gemm_8ph<<<g1, 512, 0, stream>>>(xb, wT, b_attn, qk, vT);

    dim3 g2(SEQ / 64, NHEAD, BSZ);                                      // (32,16,2)
    attn_mfma<<<g2, 256, 0, stream>>>(qk, vT, out);
}

// Round 3
// 171.803 us; speedup vs baseline: 1.0072x; 1.0072x over previous
//
#include <hip/hip_runtime.h>
#include <hip/hip_bf16.h>

// Problem constants: B=2, T=2048, C=1024, H=16, D=64
#define BSZ 2
#define SEQ 2048
#define CDIM 1024
#define NHEAD 16
#define HDIM 64
#define M_GEMM (BSZ * SEQ)      // 4096
#define N_GEMM (3 * CDIM)       // 3072
#define K_GEMM CDIM             // 1024
#define QK_PITCH (2 * CDIM)     // 2048: qk buffer row pitch (Q|K only)

typedef __attribute__((ext_vector_type(8))) short short8;   // 8 bf16 = 16B
typedef __attribute__((ext_vector_type(4))) short short4v;  // 8B
typedef __attribute__((ext_vector_type(4))) float f32x4;

__device__ __forceinline__ short bf16_rn(float f) {
    unsigned u = __builtin_bit_cast(unsigned, f);
    u += 0x7FFF + ((u >> 16) & 1);          // round-to-nearest-even
    return (short)(u >> 16);
}

// async 16B global -> LDS (wave-uniform LDS base; HW adds lane*16)
__device__ __forceinline__ void gl2lds16(const short* g, short* l) {
    __builtin_amdgcn_global_load_lds(
        (const __attribute__((address_space(1))) unsigned int*)g,
        (__attribute__((address_space(3))) unsigned int*)l, 16, 0, 0);
}

// R18 FIX: counted waits must be BARE asm (no "memory" clobber). A memory
// clobber makes the asm mayLoad|mayStore and SIInsertWaitcnts conservatively
// drains vmcnt(0) lgkmcnt(0) before it — which silently turned every phase
// boundary of R17 into a full drain (MfmaUtil 17.6%, zero overlap, 52.6us).
// Ordering across phase boundaries is pinned with sched_barrier(0) instead
// (compile-time scheduling fence: emits nothing, triggers no waitcnt).
#define WAITV4() asm volatile("s_waitcnt vmcnt(4)")
#define WAITV0() asm volatile("s_waitcnt vmcnt(0)")
#define SBAR()                                      \
    do {                                            \
        __builtin_amdgcn_sched_barrier(0);          \
        __builtin_amdgcn_s_barrier();               \
        __builtin_amdgcn_sched_barrier(0);          \
    } while (0)

// ------------- Kernel 0: fused fp32->bf16 conversions ------------------------
// blocks [0, 2048): x -> xb (same layout). blocks [2048, 2816): W -> W^T tiles.
__global__ __launch_bounds__(256) void cvt_fused(const float* __restrict__ X,
                                                 const float* __restrict__ W,
                                                 short* __restrict__ Xb,
                                                 short* __restrict__ WT) {
    const int tid = threadIdx.x;
    if (blockIdx.x < 2048) {
        size_t idx = ((size_t)blockIdx.x * 256 + tid) * 8;
        float4 a = *(const float4*)&X[idx];
        float4 b = *(const float4*)&X[idx + 4];
        short8 o;
        o[0] = bf16_rn(a.x); o[1] = bf16_rn(a.y); o[2] = bf16_rn(a.z); o[3] = bf16_rn(a.w);
        o[4] = bf16_rn(b.x); o[5] = bf16_rn(b.y); o[6] = bf16_rn(b.z); o[7] = bf16_rn(b.w);
        *(short8*)&Xb[idx] = o;
        return;
    }
    __shared__ short T[64][72];
    const int bid = blockIdx.x - 2048;          // 0..767
    const int n0 = (bid % 48) * 64;
    const int k0 = (bid / 48) * 64;
#pragma unroll
    for (int pass = 0; pass < 4; ++pass) {
        int i = pass * 256 + tid;
        int kr = i >> 4;
        int n4 = i & 15;
        float4 v = *(const float4*)&W[(size_t)(k0 + kr) * N_GEMM + n0 + n4 * 4];
        T[n4 * 4 + 0][kr] = bf16_rn(v.x);
        T[n4 * 4 + 1][kr] = bf16_rn(v.y);
        T[n4 * 4 + 2][kr] = bf16_rn(v.z);
        T[n4 * 4 + 3][kr] = bf16_rn(v.w);
    }
    __syncthreads();
#pragma unroll
    for (int pass = 0; pass < 2; ++pass) {
        int o = pass * 256 + tid;
        int nr = o >> 3;
        int c8 = o & 7;
        *(short8*)&WT[(size_t)(n0 + nr) * K_GEMM + k0 + c8 * 8] =
            *(const short8*)&T[nr][c8 * 8];
    }
}

// -------- Kernel 1: qkv = x @ W + b — 256x256 tile, 8-wave, phase-interleaved
// R18 = R17 with bare counted waits (see macro comment above). Schedule:
//  - BM=BN=256, BK=64, 8 waves (2M x 4N), per-wave C = 128x64 (acc[8][4]).
//  - LDS 128 KiB static: A[2][256][64] + B[2][256][64] bf16, chunk-XOR
//    swizzled (LDS slot s of row r holds global chunk s^(r&7); pre-swizzled
//    global source, linear LDS dest for gl2lds).
//  - 4 phases per K-tile, one C-quadrant (16 MFMA) per phase, one stage unit
//    per phase into the OTHER buffer:  ph0:AE ph1:BE ph2:BO ph3:AO, where
//    AE/AO = A rows read in phases 0-1 / 2-3, BE/BO = B rows (mod 64) <32 / >=32.
//  - counted s_waitcnt vmcnt(4) ONLY at ends of phases 0,1,3 (never 0 in the
//    loop): 4 loads (2 units) always in flight across every barrier.
//    Ledger (steady state, per wave, issue order ... AE(t)BE(t)BO(t)AO(t)AE(t+1)...):
//      end ph3: out=8 -> vmcnt(4) drains AE,BE(t+1)  [read at t+1.ph0]
//      end ph0: out=6 -> vmcnt(4) drains BO(t)       [read at ph1... wait: ph1 reads BO(t)]
//      end ph1: out=6 -> vmcnt(4) drains AO(t)       [read at ph2]
//      end ph2: nothing newly needed -> barrier only.
//    Every staged unit gets 3-4 phases (~600-1200 cyc) to land before its
//    counted drain; every ds_read is covered by issuer's drain + barrier.
//  - raw s_barrier (no vmcnt drain); staging always targets buf^1 so there is
//    no same-buffer overwrite hazard; last iter stages a dummy tile 0 to keep
//    wait counts uniform, drained by vmcnt(0) after the loop.
__global__ __launch_bounds__(512, 2) void qkv_gemm_8ph(const short* __restrict__ A,
                                                       const short* __restrict__ Bt,
                                                       const float* __restrict__ bias,
                                                       short* __restrict__ Yqk,
                                                       short* __restrict__ Yv) {
    __shared__ short Asl[32768];   // [2][256][64] bf16 = 64 KiB
    __shared__ short Bsl[32768];   // [2][256][64] bf16 = 64 KiB

    const int tid  = threadIdx.x;
    const int w    = tid >> 6;        // wave 0..7
    const int lane = tid & 63;
    const int l16  = lane & 15;
    const int quad = lane >> 4;
    const int wm   = w >> 2;          // 0..1 (M)
    const int wn   = w & 3;           // 0..3 (N)
    const int ls   = lane >> 3;       // staging: row-in-slot 0..7
    const int lc   = lane & 7;        // staging: chunk 0..7
    const int fsw  = l16 & 7;         // frag-read swizzle

    // XCD-aware bijective swizzle: XCD x gets an 8(M) x 3(N) tile patch
    // (A panels 4MB + B panels 1.5MB ~ L2-resident per XCD). 192 % 8 == 0.
    const int orig = blockIdx.y * 12 + blockIdx.x;
    const int xcd  = orig & 7;
    const int idx  = orig >> 3;                      // 0..23
    const int bM   = ((xcd & 1) << 3) + (idx & 7);   // 0..15
    const int bN   = (xcd >> 1) * 3 + (idx >> 3);    // 0..11
    const int m0   = bM << 8;
    const int n0   = bN << 8;

    const short* Ab = A  + (size_t)m0 * K_GEMM;
    const short* Bb = Bt + (size_t)n0 * K_GEMM;

    f32x4 acc[8][4];
#pragma unroll
    for (int i = 0; i < 8; ++i)
#pragma unroll
        for (int j = 0; j < 4; ++j) acc[i][j] = (f32x4){0.f, 0.f, 0.f, 0.f};

    // stage one 128-row unit (16 KiB): 2 x gl2lds per thread. LDS dest is
    // wave-uniform and linear; the global source carries the XOR pre-swizzle.
    auto stageA = [&](int unit, int tt, int sbuf) {
#pragma unroll
        for (int i = 0; i < 2; ++i) {
            const int u0 = (i * 8 + w) * 8;                       // unit row base
            const int tr = (u0 & 63) + ((u0 >> 6) << 7) + unit * 64;
            gl2lds16(Ab + (size_t)(tr + ls) * K_GEMM + tt * 64 + ((lc ^ ls) << 3),
                     &Asl[sbuf * 16384 + tr * 64]);
        }
    };
    auto stageB = [&](int unit, int tt, int sbuf) {
#pragma unroll
        for (int i = 0; i < 2; ++i) {
            const int u0 = (i * 8 + w) * 8;
            const int tr = (u0 & 31) + ((u0 >> 5) << 6) + unit * 32;
            gl2lds16(Bb + (size_t)(tr + ls) * K_GEMM + tt * 64 + ((lc ^ ls) << 3),
                     &Bsl[sbuf * 16384 + tr * 64]);
        }
    };
    auto rdA = [&](int ab, int mi, int ks) -> short8 {
        const int r = wm * 128 + mi * 16 + l16;
        return *(const short8*)&Asl[ab + r * 64 + ((ks * 4 + quad) ^ fsw) * 8];
    };
    auto rdB = [&](int ab, int ni, int ks) -> short8 {
        const int r = wn * 64 + ni * 16 + l16;
        return *(const short8*)&Bsl[ab + r * 64 + ((ks * 4 + quad) ^ fsw) * 8];
    };

    // prologue: tile 0 -> buf 0, order AE,BE,BO,AO; keep BO,AO in flight.
    stageA(0, 0, 0);
    stageB(0, 0, 0);
    stageB(1, 0, 0);
    stageA(1, 0, 0);
    WAITV4();
    SBAR();

    for (int t = 0; t < 16; ++t) {
        const int buf = t & 1;
        const int sb  = buf ^ 1;
        const int tn  = (t + 1) & 15;     // t==15 stages dummy tile 0 (uniform waits)
        const int ab  = buf * 16384;

        short8 Af[4][2], Bf[2][2];

        // ---- phase 0: (miH0 x niH0); stage AE(t+1) ----
        stageA(0, tn, sb);
#pragma unroll
        for (int mi = 0; mi < 4; ++mi)
#pragma unroll
            for (int ks = 0; ks < 2; ++ks) Af[mi][ks] = rdA(ab, mi, ks);
#pragma unroll
        for (int ni = 0; ni < 2; ++ni)
#pragma unroll
            for (int ks = 0; ks < 2; ++ks) Bf[ni][ks] = rdB(ab, ni, ks);
        __builtin_amdgcn_s_setprio(1);
#pragma unroll
        for (int mi = 0; mi < 4; ++mi)
#pragma unroll
            for (int ni = 0; ni < 2; ++ni)
#pragma unroll
                for (int ks = 0; ks < 2; ++ks)
                    acc[mi][ni] = __builtin_amdgcn_mfma_f32_16x16x32_bf16(
                        Af[mi][ks], Bf[ni][ks], acc[mi][ni], 0, 0, 0);
        __builtin_amdgcn_s_setprio(0);
        WAITV4();
        SBAR();

        // ---- phase 1: (miH0 x niH1); stage BE(t+1); Af reused ----
        stageB(0, tn, sb);
#pragma unroll
        for (int ni = 0; ni < 2; ++ni)
#pragma unroll
            for (int ks = 0; ks < 2; ++ks) Bf[ni][ks] = rdB(ab, 2 + ni, ks);
        __builtin_amdgcn_s_setprio(1);
#pragma unroll
        for (int mi = 0; mi < 4; ++mi)
#pragma unroll
            for (int ni = 0; ni < 2; ++ni)
#pragma unroll
                for (int ks = 0; ks < 2; ++ks)
                    acc[mi][2 + ni] = __builtin_amdgcn_mfma_f32_16x16x32_bf16(
                        Af[mi][ks], Bf[ni][ks], acc[mi][2 + ni], 0, 0, 0);
        __builtin_amdgcn_s_setprio(0);
        WAITV4();
        SBAR();

        // ---- phase 2: (miH1 x niH0); stage BO(t+1); no vmcnt wait ----
        stageB(1, tn, sb);
#pragma unroll
        for (int mi = 0; mi < 4; ++mi)
#pragma unroll
            for (int ks = 0; ks < 2; ++ks) Af[mi][ks] = rdA(ab, 4 + mi, ks);
#pragma unroll
        for (int ni = 0; ni < 2; ++ni)
#pragma unroll
            for (int ks = 0; ks < 2; ++ks) Bf[ni][ks] = rdB(ab, ni, ks);
        __builtin_amdgcn_s_setprio(1);
#pragma unroll
        for (int mi = 0; mi < 4; ++mi)
#pragma unroll
            for (int ni = 0; ni < 2; ++ni)
#pragma unroll
                for (int ks = 0; ks < 2; ++ks)
                    acc[4 + mi][ni] = __builtin_amdgcn_mfma_f32_16x16x32_bf16(
                        Af[mi][ks], Bf[ni][ks], acc[4 + mi][ni], 0, 0, 0);
        __builtin_amdgcn_s_setprio(0);
        SBAR();

        // ---- phase 3: (miH1 x niH1); stage AO(t+1); Af reused ----
        stageA(1, tn, sb);
#pragma unroll
        for (int ni = 0; ni < 2; ++ni)
#pragma unroll
            for (int ks = 0; ks < 2; ++ks) Bf[ni][ks] = rdB(ab, 2 + ni, ks);
        __builtin_amdgcn_s_setprio(1);
#pragma unroll
        for (int mi = 0; mi < 4; ++mi)
#pragma unroll
            for (int ni = 0; ni < 2; ++ni)
#pragma unroll
                for (int ks = 0; ks < 2; ++ks)
                    acc[4 + mi][2 + ni] = __builtin_amdgcn_mfma_f32_16x16x32_bf16(
                        Af[mi][ks], Bf[ni][ks], acc[4 + mi][2 + ni], 0, 0, 0);
        __builtin_amdgcn_s_setprio(0);
        WAITV4();
        SBAR();
    }
    WAITV0();   // drain dummy loads: no LDS-DMA may outlive the workgroup

    // ---- epilogue ----
    if (n0 >= 2 * CDIM) {
        // V block: write transposed, 4 consecutive rows packed per 8B store
#pragma unroll
        for (int mi = 0; mi < 8; ++mi) {
            int row0 = m0 + wm * 128 + mi * 16 + quad * 4;
#pragma unroll
            for (int ni = 0; ni < 4; ++ni) {
                int colg = n0 + wn * 64 + ni * 16 + l16;
                float bb = bias[colg];
                short4v pk;
#pragma unroll
                for (int r = 0; r < 4; ++r) pk[r] = bf16_rn(acc[mi][ni][r] + bb);
                *(short4v*)&Yv[(size_t)(colg - 2 * CDIM) * M_GEMM + row0] = pk;
            }
        }
    } else {
        // Q pre-scale folds BOTH 1/sqrt(64) and log2(e): attn does p = 2^s
        const float qs = (n0 < CDIM) ? 0.125f * 1.44269504f : 1.0f;
#pragma unroll
        for (int mi = 0; mi < 8; ++mi)
#pragma unroll
            for (int r = 0; r < 4; ++r) {
                int row = m0 + wm * 128 + mi * 16 + quad * 4 + r;
#pragma unroll
                for (int ni = 0; ni < 4; ++ni) {
                    int colg = n0 + wn * 64 + ni * 16 + l16;
                    Yqk[(size_t)row * QK_PITCH + colg] =
                        bf16_rn((acc[mi][ni][r] + bias[colg]) * qs);
                }
            }
    }
}

// ---------- Kernel 2: causal flash attention, scrambled-qt coset balance -----
// R14 winner; softmax uses RAW v_exp_f32 via __builtin_amdgcn_exp2f. Q carries
// 0.125*log2e from the GEMM. 64 q-rows, 4 waves x 16; dbuf K/V, one
// barrier/tile; no-max softmax; XOR swizzle; wave-private Ps; coset-balanced
// qt mapping (constant 66 tile-iters/CU, bijective per band).
__global__ __launch_bounds__(256) void attn_mfma(const short* __restrict__ qk,
                                                 const short* __restrict__ vT,
                                                 float* __restrict__ out) {
    const int b = blockIdx.z;
    const int h = blockIdx.y;
    const int bx = blockIdx.x;           // 0..31
    const int u = h + 16 * b;            // 0..31
    const int band = u >> 3;             // 0..3
    const int base = (band & 2) ? ((bx + 16) & 31) : bx;
    const int qt = (band & 1) ? (31 - base) : base;
    const int tid = threadIdx.x;
    const int w = tid >> 6;
    const int lane = tid & 63;
    const int quad = lane >> 4;
    const int l16 = lane & 15;
    const int q0 = qt * 64;

    __shared__ short Ks[2][64 * 64];     // [buf][key][d], chunk-swizzled 16 KB
    __shared__ short Vt[2][64 * 64];     // [buf][d][key], chunk-swizzled 16 KB
    __shared__ short Ps[4 * 16 * 64];    // per-wave [q][key]              8 KB

    // staging descriptors: issue p covers chunks cid = p*256 + w*64 + lane
    int koff[2], voff[2], ldso[2];
#pragma unroll
    for (int p = 0; p < 2; ++p) {
        int cid = p * 256 + w * 64 + lane;
        int row = cid >> 3;
        int c = (cid & 7) ^ (row & 7);
        koff[p] = row * QK_PITCH + c * 8;
        voff[p] = row * M_GEMM + c * 8;
        ldso[p] = (p * 256 + w * 64) * 8;    // wave-uniform chunk base (shorts)
    }

    // Q fragments (A-layout: A[m=l16][k=quad*8+j])
    const short* qrow = qk + (size_t)(b * SEQ + q0 + w * 16 + l16) * QK_PITCH + h * HDIM;
    short8 aq[2];
    aq[0] = *(const short8*)(qrow + quad * 8);
    aq[1] = *(const short8*)(qrow + 32 + quad * 8);

    float l_run[4] = {0.f, 0.f, 0.f, 0.f};
    f32x4 o_acc[4];
#pragma unroll
    for (int dt = 0; dt < 4; ++dt) o_acc[dt] = (f32x4){0.f, 0.f, 0.f, 0.f};

    const int rowg0 = q0 + w * 16 + quad * 4;
    const short* kb0 = qk + (size_t)(b * SEQ) * QK_PITCH + CDIM + h * HDIM;
    const short* vb0 = vT + (size_t)(h * HDIM) * M_GEMM + b * SEQ;

    const int ksl = l16 & 7;
    short* PsW = &Ps[w * 1024];

    // prologue: stage tile 0 into buf 0
#pragma unroll
    for (int p = 0; p < 2; ++p) {
        gl2lds16(kb0 + koff[p], &Ks[0][ldso[p]]);
        gl2lds16(vb0 + voff[p], &Vt[0][ldso[p]]);
    }
    __syncthreads();                     // prologue staging drained

    for (int kt = 0; kt <= qt; ++kt) {
        const int cur = kt & 1;

        // prefetch tile kt+1 into the other buffer (overlaps compute)
        if (kt < qt) {
            const short* kbase = kb0 + (size_t)(kt + 1) * 64 * QK_PITCH;
            const short* vbase = vb0 + (kt + 1) * 64;
#pragma unroll
            for (int p = 0; p < 2; ++p) {
                gl2lds16(kbase + koff[p], &Ks[cur ^ 1][ldso[p]]);
                gl2lds16(vbase + voff[p], &Vt[cur ^ 1][ldso[p]]);
            }
        }

        const short* KsC = Ks[cur];
        const short* VtC = Vt[cur];

        // ---- QK^T: S[16 q][64 keys] (s already includes log2e factor) ----
        f32x4 s[4];
#pragma unroll
        for (int nt = 0; nt < 4; ++nt) s[nt] = (f32x4){0.f, 0.f, 0.f, 0.f};
#pragma unroll
        for (int nt = 0; nt < 4; ++nt)
#pragma unroll
            for (int ks = 0; ks < 2; ++ks) {
                short8 bk = *(const short8*)&KsC[(nt * 16 + l16) * 64 +
                                                 ((ks * 4 + quad) ^ ksl) * 8];
                s[nt] = __builtin_amdgcn_mfma_f32_16x16x32_bf16(aq[ks], bk, s[nt], 0, 0, 0);
            }

        // ---- no-max softmax: p = 2^s, ONE v_exp_f32 each; lane-local l ----
        if (kt < qt) {                   // full tile, wave-uniform
#pragma unroll
            for (int r = 0; r < 4; ++r) {
                const int qr = quad * 4 + r;
                float lsum = 0.f;
#pragma unroll
                for (int nt = 0; nt < 4; ++nt) {
                    float pp = __builtin_amdgcn_exp2f(s[nt][r]);
                    lsum += pp;
                    int slot = (nt * 2 + (l16 >> 3)) ^ (qr & 7);
                    PsW[qr * 64 + slot * 8 + (l16 & 7)] = bf16_rn(pp);
                }
                l_run[r] += lsum;
            }
        } else {                         // diagonal tile: causal mask
            const int keyb = kt * 64 + l16;
#pragma unroll
            for (int r = 0; r < 4; ++r) {
                const int qr = quad * 4 + r;
                const int rowg = rowg0 + r;
                float lsum = 0.f;
#pragma unroll
                for (int nt = 0; nt < 4; ++nt) {
                    float pp = __builtin_amdgcn_exp2f(s[nt][r]);
                    pp = ((keyb + nt * 16) > rowg) ? 0.f : pp;
                    lsum += pp;
                    int slot = (nt * 2 + (l16 >> 3)) ^ (qr & 7);
                    PsW[qr * 64 + slot * 8 + (l16 & 7)] = bf16_rn(pp);
                }
                l_run[r] += lsum;
            }
        }

        // ---- PV: O[16 q][64 d] += P @ V (Ps wave-private; no barrier) ----
#pragma unroll
        for (int dt = 0; dt < 4; ++dt)
#pragma unroll
            for (int ks = 0; ks < 2; ++ks) {
                short8 ap = *(const short8*)&PsW[l16 * 64 + ((ks * 4 + quad) ^ ksl) * 8];
                short8 bv = *(const short8*)&VtC[(dt * 16 + l16) * 64 +
                                                 ((ks * 4 + quad) ^ ksl) * 8];
                o_acc[dt] = __builtin_amdgcn_mfma_f32_16x16x32_bf16(ap, bv, o_acc[dt], 0, 0, 0);
            }

        // one barrier/tile: drains prefetch + guards buffer reuse
        __syncthreads();
    }

    // ---- epilogue: reduce l across the 16 key-lanes, normalize, store ----
#pragma unroll
    for (int r = 0; r < 4; ++r) {
        float l = l_run[r];
#pragma unroll
        for (int off = 1; off < 16; off <<= 1)
            l += __shfl_xor(l, off);
        float inv = 1.f / l;
        int row = q0 + w * 16 + quad * 4 + r;
        float* optr = out + (size_t)(b * SEQ + row) * CDIM + h * HDIM;
#pragma unroll
        for (int dt = 0; dt < 4; ++dt)
            optr[dt * 16 + l16] = o_acc[dt][r] * inv;
    }
}

// ------------------------------- launch --------------------------------------
extern "C" void kernel_launch(void* const* d_in, const int* in_sizes, int n_in,
                              void* d_out, int out_size, void* d_ws, size_t ws_size,
                              hipStream_t stream) {
    const float* x      = (const float*)d_in[0];   // [B,T,C] fp32
    const float* w_attn = (const float*)d_in[1];   // [C,3C]  fp32
    const float* b_attn = (const float*)d_in[2];   // [3C]    fp32
    float* out = (float*)d_out;                    // [B,T,C] fp32

    // workspace: qk [4096][2048] 16.78MB | vT [1024][4096] 8.39MB | xb 8.39MB | wT 6.29MB
    short* qk  = (short*)d_ws;
    short* vT  = (short*)((char*)d_ws + 16777216);
    short* xb  = (short*)((char*)d_ws + 25165824);
    short* wT  = (short*)((char*)d_ws + 33554432);

    cvt_fused<<<2048 + 768, 256, 0, stream>>>(x, w_attn, xb, wT);

    dim3 g1(N_GEMM / 256, M_GEMM / 256);                                // (12,16)
    qkv_gemm_8ph<<<g1, 512, 0, stream>>>(xb, wT, b_attn, qk, vT);

    dim3 g2(SEQ / 64, NHEAD, BSZ);                                      // (32,16,2)
    attn_mfma<<<g2, 256, 0, stream>>>(qk, vT, out);
}

// Round 4
// 157.957 us; speedup vs baseline: 1.0955x; 1.0877x over previous
//
#include <hip/hip_runtime.h>
#include <hip/hip_bf16.h>

// Problem constants: B=2, T=2048, C=1024, H=16, D=64
#define BSZ 2
#define SEQ 2048
#define CDIM 1024
#define NHEAD 16
#define HDIM 64
#define M_GEMM (BSZ * SEQ)      // 4096
#define N_GEMM (3 * CDIM)       // 3072
#define K_GEMM CDIM             // 1024
#define QK_PITCH (2 * CDIM)     // 2048: qk buffer row pitch (Q|K only)

typedef __attribute__((ext_vector_type(8))) short short8;   // 8 bf16 = 16B
typedef __attribute__((ext_vector_type(4))) short short4v;  // 8B
typedef __attribute__((ext_vector_type(4))) float f32x4;

__device__ __forceinline__ short bf16_rn(float f) {
    unsigned u = __builtin_bit_cast(unsigned, f);
    u += 0x7FFF + ((u >> 16) & 1);          // round-to-nearest-even
    return (short)(u >> 16);
}

// async 16B global -> LDS (wave-uniform LDS base; HW adds lane*16)
__device__ __forceinline__ void gl2lds16(const short* g, short* l) {
    __builtin_amdgcn_global_load_lds(
        (const __attribute__((address_space(1))) unsigned int*)g,
        (__attribute__((address_space(3))) unsigned int*)l, 16, 0, 0);
}

// bare counted waits (NO "memory" clobber: that forces a full vmcnt0/lgkmcnt0
// drain by SIInsertWaitcnts). Ordering pinned with sched_barrier(0) instead.
#define WAITV4() asm volatile("s_waitcnt vmcnt(4)")
#define WAITV0() asm volatile("s_waitcnt vmcnt(0)")
#define LGKM0()  asm volatile("s_waitcnt lgkmcnt(0)")
#define SCB()    __builtin_amdgcn_sched_barrier(0)
#define BARRIER() __builtin_amdgcn_s_barrier()

// ------------- Kernel 0: fused fp32->bf16 conversions ------------------------
// blocks [0, 2048): x -> xb (same layout). blocks [2048, 2816): W -> W^T tiles.
__global__ __launch_bounds__(256) void cvt_fused(const float* __restrict__ X,
                                                 const float* __restrict__ W,
                                                 short* __restrict__ Xb,
                                                 short* __restrict__ WT) {
    const int tid = threadIdx.x;
    if (blockIdx.x < 2048) {
        size_t idx = ((size_t)blockIdx.x * 256 + tid) * 8;
        float4 a = *(const float4*)&X[idx];
        float4 b = *(const float4*)&X[idx + 4];
        short8 o;
        o[0] = bf16_rn(a.x); o[1] = bf16_rn(a.y); o[2] = bf16_rn(a.z); o[3] = bf16_rn(a.w);
        o[4] = bf16_rn(b.x); o[5] = bf16_rn(b.y); o[6] = bf16_rn(b.z); o[7] = bf16_rn(b.w);
        *(short8*)&Xb[idx] = o;
        return;
    }
    __shared__ short T[64][72];
    const int bid = blockIdx.x - 2048;          // 0..767
    const int n0 = (bid % 48) * 64;
    const int k0 = (bid / 48) * 64;
#pragma unroll
    for (int pass = 0; pass < 4; ++pass) {
        int i = pass * 256 + tid;
        int kr = i >> 4;
        int n4 = i & 15;
        float4 v = *(const float4*)&W[(size_t)(k0 + kr) * N_GEMM + n0 + n4 * 4];
        T[n4 * 4 + 0][kr] = bf16_rn(v.x);
        T[n4 * 4 + 1][kr] = bf16_rn(v.y);
        T[n4 * 4 + 2][kr] = bf16_rn(v.z);
        T[n4 * 4 + 3][kr] = bf16_rn(v.w);
    }
    __syncthreads();
#pragma unroll
    for (int pass = 0; pass < 2; ++pass) {
        int o = pass * 256 + tid;
        int nr = o >> 3;
        int c8 = o & 7;
        *(short8*)&WT[(size_t)(n0 + nr) * K_GEMM + k0 + c8 * 8] =
            *(const short8*)&T[nr][c8 * 8];
    }
}

// -------- Kernel 1: qkv = x @ W + b — 256x256 tile, 8-wave, m201-style phases
// R19: the phase internals now follow the VERIFIED m201 template exactly:
//   { ds_reads for THIS phase's quadrant -> stage 1 unit ->
//     s_barrier -> lgkmcnt(0) -> sched_barrier ->
//     setprio(1) -> 16 MFMA -> setprio(0) -> [vmcnt(4)] -> s_barrier }
// TWO barriers per phase: ds_reads are issued BEFORE a barrier and waited
// AFTER it, so waves de-phase into reader/MFMA roles instead of lockstep
// (R17/R18's single-barrier lockstep left LDS idle during MFMA and vice
// versa -> 54us). B-fragments for all 4 ni are kept live in registers
// (loaded ph0/ph1, reused ph2/ph3): per-wave LDS reads drop 32->24 KB/tile.
//  - BM=BN=256, BK=64, 8 waves (2M x 4N), per-wave C = 128x64 (acc[8][4]).
//  - LDS 128 KiB static, chunk-XOR swizzle (slot s of row r holds global
//    chunk s^(r&7)); pre-swizzled global source, linear LDS dest for gl2lds.
//  - stage units per phase into the OTHER buffer: ph0:AE ph1:BE ph2:BO ph3:AO
//    (AE/AO = A rows for phases 0-1 / 2-3; BE/BO = B rows (mod 64) <32 / >=32).
//  - vmcnt(4) before the CLOSING barrier of phases 0,1,3 (never 0 in loop).
//    A wave's vmcnt covers only its own loads; the following barrier is what
//    publishes them to other waves. Ledger (steady state, per wave):
//      entering ph0(t): outstanding = BO(t),AO(t); ph0 reads AE/BE(t)
//        (drained at end-ph3(t-1)); ph0 issues AE(t+1) -> out=6
//      end-ph0 vmcnt(4): drains BO(t)   [read in ph1]
//      end-ph1 vmcnt(4): drains AO(t)   [read in ph2]   (ph1 issued BE(t+1))
//      ph2 issues BO(t+1), no wait; ph3 issues AO(t+1) -> out=8
//      end-ph3 vmcnt(4): drains AE,BE(t+1) [read in ph0(t+1)]
//  - last iter stages a dummy tile 0 (uniform waits), drained by vmcnt(0)
//    after the loop so no LDS-DMA outlives the workgroup.
#define MFMA_QUAD(MB, NB)                                                     \
    do {                                                                      \
        __builtin_amdgcn_s_setprio(1);                                        \
        _Pragma("unroll")                                                     \
        for (int mi_ = 0; mi_ < 4; ++mi_)                                     \
            _Pragma("unroll")                                                 \
            for (int ni_ = 0; ni_ < 2; ++ni_)                                 \
                _Pragma("unroll")                                             \
                for (int ks_ = 0; ks_ < 2; ++ks_)                             \
                    acc[(MB) + mi_][(NB) + ni_] =                             \
                        __builtin_amdgcn_mfma_f32_16x16x32_bf16(              \
                            Af[mi_][ks_], Bf[(NB) + ni_][ks_],                \
                            acc[(MB) + mi_][(NB) + ni_], 0, 0, 0);            \
        __builtin_amdgcn_s_setprio(0);                                        \
    } while (0)

__global__ __launch_bounds__(512, 2) void qkv_gemm_8ph(const short* __restrict__ A,
                                                       const short* __restrict__ Bt,
                                                       const float* __restrict__ bias,
                                                       short* __restrict__ Yqk,
                                                       short* __restrict__ Yv) {
    __shared__ short Asl[32768];   // [2][256][64] bf16 = 64 KiB
    __shared__ short Bsl[32768];   // [2][256][64] bf16 = 64 KiB

    const int tid  = threadIdx.x;
    const int w    = tid >> 6;        // wave 0..7
    const int lane = tid & 63;
    const int l16  = lane & 15;
    const int quad = lane >> 4;
    const int wm   = w >> 2;          // 0..1 (M)
    const int wn   = w & 3;           // 0..3 (N)
    const int ls   = lane >> 3;       // staging: row-in-slot 0..7
    const int lc   = lane & 7;        // staging: chunk 0..7
    const int fsw  = l16 & 7;         // frag-read swizzle

    // XCD-aware bijective swizzle: XCD x gets an 8(M) x 3(N) tile patch
    // (A panels 4MB + B panels 1.5MB ~ L2-resident per XCD). 192 % 8 == 0.
    const int orig = blockIdx.y * 12 + blockIdx.x;
    const int xcd  = orig & 7;
    const int idx  = orig >> 3;                      // 0..23
    const int bM   = ((xcd & 1) << 3) + (idx & 7);   // 0..15
    const int bN   = (xcd >> 1) * 3 + (idx >> 3);    // 0..11
    const int m0   = bM << 8;
    const int n0   = bN << 8;

    const short* Ab = A  + (size_t)m0 * K_GEMM;
    const short* Bb = Bt + (size_t)n0 * K_GEMM;

    f32x4 acc[8][4];
#pragma unroll
    for (int i = 0; i < 8; ++i)
#pragma unroll
        for (int j = 0; j < 4; ++j) acc[i][j] = (f32x4){0.f, 0.f, 0.f, 0.f};

    // stage one 128-row unit (16 KiB): 2 x gl2lds per thread. LDS dest is
    // wave-uniform and linear; the global source carries the XOR pre-swizzle.
    auto stageA = [&](int unit, int tt, int sbuf) {
#pragma unroll
        for (int i = 0; i < 2; ++i) {
            const int u0 = (i * 8 + w) * 8;                       // unit row base
            const int tr = (u0 & 63) + ((u0 >> 6) << 7) + unit * 64;
            gl2lds16(Ab + (size_t)(tr + ls) * K_GEMM + tt * 64 + ((lc ^ ls) << 3),
                     &Asl[sbuf * 16384 + tr * 64]);
        }
    };
    auto stageB = [&](int unit, int tt, int sbuf) {
#pragma unroll
        for (int i = 0; i < 2; ++i) {
            const int u0 = (i * 8 + w) * 8;
            const int tr = (u0 & 31) + ((u0 >> 5) << 6) + unit * 32;
            gl2lds16(Bb + (size_t)(tr + ls) * K_GEMM + tt * 64 + ((lc ^ ls) << 3),
                     &Bsl[sbuf * 16384 + tr * 64]);
        }
    };
    auto rdA = [&](int ab, int mi, int ks) -> short8 {
        const int r = wm * 128 + mi * 16 + l16;
        return *(const short8*)&Asl[ab + r * 64 + ((ks * 4 + quad) ^ fsw) * 8];
    };
    auto rdB = [&](int ab, int ni, int ks) -> short8 {
        const int r = wn * 64 + ni * 16 + l16;
        return *(const short8*)&Bsl[ab + r * 64 + ((ks * 4 + quad) ^ fsw) * 8];
    };

    // prologue: tile 0 -> buf 0, order AE,BE,BO,AO; keep BO,AO in flight.
    stageA(0, 0, 0);
    stageB(0, 0, 0);
    stageB(1, 0, 0);
    stageA(1, 0, 0);
    WAITV4();
    SCB();
    BARRIER();
    SCB();

    for (int t = 0; t < 16; ++t) {
        const int buf = t & 1;
        const int sb  = buf ^ 1;
        const int tn  = (t + 1) & 15;     // t==15 stages dummy tile 0 (uniform waits)
        const int ab  = buf * 16384;

        short8 Af[4][2], Bf[4][2];

        // ================= phase 0: quadrant (miH0 x niH0) ===================
#pragma unroll
        for (int mi = 0; mi < 4; ++mi)
#pragma unroll
            for (int ks = 0; ks < 2; ++ks) Af[mi][ks] = rdA(ab, mi, ks);
#pragma unroll
        for (int ni = 0; ni < 2; ++ni)
#pragma unroll
            for (int ks = 0; ks < 2; ++ks) Bf[ni][ks] = rdB(ab, ni, ks);
        stageA(0, tn, sb);
        SCB(); BARRIER(); LGKM0(); SCB();
        MFMA_QUAD(0, 0);
        WAITV4();
        SCB(); BARRIER(); SCB();

        // ================= phase 1: quadrant (miH0 x niH1) ===================
#pragma unroll
        for (int ni = 2; ni < 4; ++ni)
#pragma unroll
            for (int ks = 0; ks < 2; ++ks) Bf[ni][ks] = rdB(ab, ni, ks);
        stageB(0, tn, sb);
        SCB(); BARRIER(); LGKM0(); SCB();
        MFMA_QUAD(0, 2);
        WAITV4();
        SCB(); BARRIER(); SCB();

        // ===== phase 2: quadrant (miH1 x niH0); Bf[0..1] reused from regs ====
#pragma unroll
        for (int mi = 0; mi < 4; ++mi)
#pragma unroll
            for (int ks = 0; ks < 2; ++ks) Af[mi][ks] = rdA(ab, 4 + mi, ks);
        stageB(1, tn, sb);
        SCB(); BARRIER(); LGKM0(); SCB();
        MFMA_QUAD(4, 0);
        SCB(); BARRIER(); SCB();          // no vmcnt here

        // ===== phase 3: quadrant (miH1 x niH1); Af + Bf[2..3] from regs ======
        stageA(1, tn, sb);
        SCB(); BARRIER(); SCB();
        MFMA_QUAD(4, 2);
        WAITV4();
        SCB(); BARRIER(); SCB();
    }
    WAITV0();   // drain dummy loads: no LDS-DMA may outlive the workgroup

    // ---- epilogue ----
    if (n0 >= 2 * CDIM) {
        // V block: write transposed, 4 consecutive rows packed per 8B store
#pragma unroll
        for (int mi = 0; mi < 8; ++mi) {
            int row0 = m0 + wm * 128 + mi * 16 + quad * 4;
#pragma unroll
            for (int ni = 0; ni < 4; ++ni) {
                int colg = n0 + wn * 64 + ni * 16 + l16;
                float bb = bias[colg];
                short4v pk;
#pragma unroll
                for (int r = 0; r < 4; ++r) pk[r] = bf16_rn(acc[mi][ni][r] + bb);
                *(short4v*)&Yv[(size_t)(colg - 2 * CDIM) * M_GEMM + row0] = pk;
            }
        }
    } else {
        // Q pre-scale folds BOTH 1/sqrt(64) and log2(e): attn does p = 2^s
        const float qs = (n0 < CDIM) ? 0.125f * 1.44269504f : 1.0f;
#pragma unroll
        for (int mi = 0; mi < 8; ++mi)
#pragma unroll
            for (int r = 0; r < 4; ++r) {
                int row = m0 + wm * 128 + mi * 16 + quad * 4 + r;
#pragma unroll
                for (int ni = 0; ni < 4; ++ni) {
                    int colg = n0 + wn * 64 + ni * 16 + l16;
                    Yqk[(size_t)row * QK_PITCH + colg] =
                        bf16_rn((acc[mi][ni][r] + bias[colg]) * qs);
                }
            }
    }
}

// ---------- Kernel 2: causal flash attention, scrambled-qt coset balance -----
// R14 winner; softmax uses RAW v_exp_f32 via __builtin_amdgcn_exp2f. Q carries
// 0.125*log2e from the GEMM. 64 q-rows, 4 waves x 16; dbuf K/V, one
// barrier/tile; no-max softmax; XOR swizzle; wave-private Ps; coset-balanced
// qt mapping (constant 66 tile-iters/CU, bijective per band).
__global__ __launch_bounds__(256) void attn_mfma(const short* __restrict__ qk,
                                                 const short* __restrict__ vT,
                                                 float* __restrict__ out) {
    const int b = blockIdx.z;
    const int h = blockIdx.y;
    const int bx = blockIdx.x;           // 0..31
    const int u = h + 16 * b;            // 0..31
    const int band = u >> 3;             // 0..3
    const int base = (band & 2) ? ((bx + 16) & 31) : bx;
    const int qt = (band & 1) ? (31 - base) : base;
    const int tid = threadIdx.x;
    const int w = tid >> 6;
    const int lane = tid & 63;
    const int quad = lane >> 4;
    const int l16 = lane & 15;
    const int q0 = qt * 64;

    __shared__ short Ks[2][64 * 64];     // [buf][key][d], chunk-swizzled 16 KB
    __shared__ short Vt[2][64 * 64];     // [buf][d][key], chunk-swizzled 16 KB
    __shared__ short Ps[4 * 16 * 64];    // per-wave [q][key]              8 KB

    // staging descriptors: issue p covers chunks cid = p*256 + w*64 + lane
    int koff[2], voff[2], ldso[2];
#pragma unroll
    for (int p = 0; p < 2; ++p) {
        int cid = p * 256 + w * 64 + lane;
        int row = cid >> 3;
        int c = (cid & 7) ^ (row & 7);
        koff[p] = row * QK_PITCH + c * 8;
        voff[p] = row * M_GEMM + c * 8;
        ldso[p] = (p * 256 + w * 64) * 8;    // wave-uniform chunk base (shorts)
    }

    // Q fragments (A-layout: A[m=l16][k=quad*8+j])
    const short* qrow = qk + (size_t)(b * SEQ + q0 + w * 16 + l16) * QK_PITCH + h * HDIM;
    short8 aq[2];
    aq[0] = *(const short8*)(qrow + quad * 8);
    aq[1] = *(const short8*)(qrow + 32 + quad * 8);

    float l_run[4] = {0.f, 0.f, 0.f, 0.f};
    f32x4 o_acc[4];
#pragma unroll
    for (int dt = 0; dt < 4; ++dt) o_acc[dt] = (f32x4){0.f, 0.f, 0.f, 0.f};

    const int rowg0 = q0 + w * 16 + quad * 4;
    const short* kb0 = qk + (size_t)(b * SEQ) * QK_PITCH + CDIM + h * HDIM;
    const short* vb0 = vT + (size_t)(h * HDIM) * M_GEMM + b * SEQ;

    const int ksl = l16 & 7;
    short* PsW = &Ps[w * 1024];

    // prologue: stage tile 0 into buf 0
#pragma unroll
    for (int p = 0; p < 2; ++p) {
        gl2lds16(kb0 + koff[p], &Ks[0][ldso[p]]);
        gl2lds16(vb0 + voff[p], &Vt[0][ldso[p]]);
    }
    __syncthreads();                     // prologue staging drained

    for (int kt = 0; kt <= qt; ++kt) {
        const int cur = kt & 1;

        // prefetch tile kt+1 into the other buffer (overlaps compute)
        if (kt < qt) {
            const short* kbase = kb0 + (size_t)(kt + 1) * 64 * QK_PITCH;
            const short* vbase = vb0 + (kt + 1) * 64;
#pragma unroll
            for (int p = 0; p < 2; ++p) {
                gl2lds16(kbase + koff[p], &Ks[cur ^ 1][ldso[p]]);
                gl2lds16(vbase + voff[p], &Vt[cur ^ 1][ldso[p]]);
            }
        }

        const short* KsC = Ks[cur];
        const short* VtC = Vt[cur];

        // ---- QK^T: S[16 q][64 keys] (s already includes log2e factor) ----
        f32x4 s[4];
#pragma unroll
        for (int nt = 0; nt < 4; ++nt) s[nt] = (f32x4){0.f, 0.f, 0.f, 0.f};
#pragma unroll
        for (int nt = 0; nt < 4; ++nt)
#pragma unroll
            for (int ks = 0; ks < 2; ++ks) {
                short8 bk = *(const short8*)&KsC[(nt * 16 + l16) * 64 +
                                                 ((ks * 4 + quad) ^ ksl) * 8];
                s[nt] = __builtin_amdgcn_mfma_f32_16x16x32_bf16(aq[ks], bk, s[nt], 0, 0, 0);
            }

        // ---- no-max softmax: p = 2^s, ONE v_exp_f32 each; lane-local l ----
        if (kt < qt) {                   // full tile, wave-uniform
#pragma unroll
            for (int r = 0; r < 4; ++r) {
                const int qr = quad * 4 + r;
                float lsum = 0.f;
#pragma unroll
                for (int nt = 0; nt < 4; ++nt) {
                    float pp = __builtin_amdgcn_exp2f(s[nt][r]);
                    lsum += pp;
                    int slot = (nt * 2 + (l16 >> 3)) ^ (qr & 7);
                    PsW[qr * 64 + slot * 8 + (l16 & 7)] = bf16_rn(pp);
                }
                l_run[r] += lsum;
            }
        } else {                         // diagonal tile: causal mask
            const int keyb = kt * 64 + l16;
#pragma unroll
            for (int r = 0; r < 4; ++r) {
                const int qr = quad * 4 + r;
                const int rowg = rowg0 + r;
                float lsum = 0.f;
#pragma unroll
                for (int nt = 0; nt < 4; ++nt) {
                    float pp = __builtin_amdgcn_exp2f(s[nt][r]);
                    pp = ((keyb + nt * 16) > rowg) ? 0.f : pp;
                    lsum += pp;
                    int slot = (nt * 2 + (l16 >> 3)) ^ (qr & 7);
                    PsW[qr * 64 + slot * 8 + (l16 & 7)] = bf16_rn(pp);
                }
                l_run[r] += lsum;
            }
        }

        // ---- PV: O[16 q][64 d] += P @ V (Ps wave-private; no barrier) ----
#pragma unroll
        for (int dt = 0; dt < 4; ++dt)
#pragma unroll
            for (int ks = 0; ks < 2; ++ks) {
                short8 ap = *(const short8*)&PsW[l16 * 64 + ((ks * 4 + quad) ^ ksl) * 8];
                short8 bv = *(const short8*)&VtC[(dt * 16 + l16) * 64 +
                                                 ((ks * 4 + quad) ^ ksl) * 8];
                o_acc[dt] = __builtin_amdgcn_mfma_f32_16x16x32_bf16(ap, bv, o_acc[dt], 0, 0, 0);
            }

        // one barrier/tile: drains prefetch + guards buffer reuse
        __syncthreads();
    }

    // ---- epilogue: reduce l across the 16 key-lanes, normalize, store ----
#pragma unroll
    for (int r = 0; r < 4; ++r) {
        float l = l_run[r];
#pragma unroll
        for (int off = 1; off < 16; off <<= 1)
            l += __shfl_xor(l, off);
        float inv = 1.f / l;
        int row = q0 + w * 16 + quad * 4 + r;
        float* optr = out + (size_t)(b * SEQ + row) * CDIM + h * HDIM;
#pragma unroll
        for (int dt = 0; dt < 4; ++dt)
            optr[dt * 16 + l16] = o_acc[dt][r] * inv;
    }
}

// ------------------------------- launch --------------------------------------
extern "C" void kernel_launch(void* const* d_in, const int* in_sizes, int n_in,
                              void* d_out, int out_size, void* d_ws, size_t ws_size,
                              hipStream_t stream) {
    const float* x      = (const float*)d_in[0];   // [B,T,C] fp32
    const float* w_attn = (const float*)d_in[1];   // [C,3C]  fp32
    const float* b_attn = (const float*)d_in[2];   // [3C]    fp32
    float* out = (float*)d_out;                    // [B,T,C] fp32

    // workspace: qk [4096][2048] 16.78MB | vT [1024][4096] 8.39MB | xb 8.39MB | wT 6.29MB
    short* qk  = (short*)d_ws;
    short* vT  = (short*)((char*)d_ws + 16777216);
    short* xb  = (short*)((char*)d_ws + 25165824);
    short* wT  = (short*)((char*)d_ws + 33554432);

    cvt_fused<<<2048 + 768, 256, 0, stream>>>(x, w_attn, xb, wT);

    dim3 g1(N_GEMM / 256, M_GEMM / 256);                                // (12,16)
    qkv_gemm_8ph<<<g1, 512, 0, stream>>>(xb, wT, b_attn, qk, vT);

    dim3 g2(SEQ / 64, NHEAD, BSZ);                                      // (32,16,2)
    attn_mfma<<<g2, 256, 0, stream>>>(qk, vT, out);
}

// Round 5
// 154.707 us; speedup vs baseline: 1.1185x; 1.0210x over previous
//
#include <hip/hip_runtime.h>
#include <hip/hip_bf16.h>

// Problem constants: B=2, T=2048, C=1024, H=16, D=64
#define BSZ 2
#define SEQ 2048
#define CDIM 1024
#define NHEAD 16
#define HDIM 64
#define M_GEMM (BSZ * SEQ)      // 4096
#define N_GEMM (3 * CDIM)       // 3072
#define K_GEMM CDIM             // 1024
#define QK_PITCH (2 * CDIM)     // 2048: qk buffer row pitch (Q|K only)

typedef __attribute__((ext_vector_type(8))) short short8;   // 8 bf16 = 16B
typedef __attribute__((ext_vector_type(4))) short short4v;  // 8B
typedef __attribute__((ext_vector_type(4))) float f32x4;

__device__ __forceinline__ short bf16_rn(float f) {
    unsigned u = __builtin_bit_cast(unsigned, f);
    u += 0x7FFF + ((u >> 16) & 1);          // round-to-nearest-even
    return (short)(u >> 16);
}

// async 16B global -> LDS (wave-uniform LDS base; HW adds lane*16)
__device__ __forceinline__ void gl2lds16(const short* g, short* l) {
    __builtin_amdgcn_global_load_lds(
        (const __attribute__((address_space(1))) unsigned int*)g,
        (__attribute__((address_space(3))) unsigned int*)l, 16, 0, 0);
}

// bare counted waits (NO "memory" clobber: that forces a full vmcnt0/lgkmcnt0
// drain by SIInsertWaitcnts). Ordering pinned with sched_barrier(0) instead.
#define WAITV4() asm volatile("s_waitcnt vmcnt(4)")
#define WAITV0() asm volatile("s_waitcnt vmcnt(0)")
#define LGKM0()  asm volatile("s_waitcnt lgkmcnt(0)")
#define SCB()    __builtin_amdgcn_sched_barrier(0)
#define BARRIER() __builtin_amdgcn_s_barrier()

// ------------- Kernel 0: fused fp32->bf16 conversions ------------------------
// blocks [0, 2048): x -> xb (same layout). blocks [2048, 2816): W -> W^T tiles.
__global__ __launch_bounds__(256) void cvt_fused(const float* __restrict__ X,
                                                 const float* __restrict__ W,
                                                 short* __restrict__ Xb,
                                                 short* __restrict__ WT) {
    const int tid = threadIdx.x;
    if (blockIdx.x < 2048) {
        size_t idx = ((size_t)blockIdx.x * 256 + tid) * 8;
        float4 a = *(const float4*)&X[idx];
        float4 b = *(const float4*)&X[idx + 4];
        short8 o;
        o[0] = bf16_rn(a.x); o[1] = bf16_rn(a.y); o[2] = bf16_rn(a.z); o[3] = bf16_rn(a.w);
        o[4] = bf16_rn(b.x); o[5] = bf16_rn(b.y); o[6] = bf16_rn(b.z); o[7] = bf16_rn(b.w);
        *(short8*)&Xb[idx] = o;
        return;
    }
    __shared__ short T[64][72];
    const int bid = blockIdx.x - 2048;          // 0..767
    const int n0 = (bid % 48) * 64;
    const int k0 = (bid / 48) * 64;
#pragma unroll
    for (int pass = 0; pass < 4; ++pass) {
        int i = pass * 256 + tid;
        int kr = i >> 4;
        int n4 = i & 15;
        float4 v = *(const float4*)&W[(size_t)(k0 + kr) * N_GEMM + n0 + n4 * 4];
        T[n4 * 4 + 0][kr] = bf16_rn(v.x);
        T[n4 * 4 + 1][kr] = bf16_rn(v.y);
        T[n4 * 4 + 2][kr] = bf16_rn(v.z);
        T[n4 * 4 + 3][kr] = bf16_rn(v.w);
    }
    __syncthreads();
#pragma unroll
    for (int pass = 0; pass < 2; ++pass) {
        int o = pass * 256 + tid;
        int nr = o >> 3;
        int c8 = o & 7;
        *(short8*)&WT[(size_t)(n0 + nr) * K_GEMM + k0 + c8 * 8] =
            *(const short8*)&T[nr][c8 * 8];
    }
}

// -------- Kernel 1: qkv = x @ W + b — 256x256 tile, 8-wave, m201-style phases
// R19 winner (171.8 -> 158.0 total): two barriers per phase, ds_reads issued
// BEFORE a barrier and lgkm-waited AFTER it, counted vmcnt(4) never 0 in loop.
#define MFMA_QUAD(MB, NB)                                                     \
    do {                                                                      \
        __builtin_amdgcn_s_setprio(1);                                        \
        _Pragma("unroll")                                                     \
        for (int mi_ = 0; mi_ < 4; ++mi_)                                     \
            _Pragma("unroll")                                                 \
            for (int ni_ = 0; ni_ < 2; ++ni_)                                 \
                _Pragma("unroll")                                             \
                for (int ks_ = 0; ks_ < 2; ++ks_)                             \
                    acc[(MB) + mi_][(NB) + ni_] =                             \
                        __builtin_amdgcn_mfma_f32_16x16x32_bf16(              \
                            Af[mi_][ks_], Bf[(NB) + ni_][ks_],                \
                            acc[(MB) + mi_][(NB) + ni_], 0, 0, 0);            \
        __builtin_amdgcn_s_setprio(0);                                        \
    } while (0)

__global__ __launch_bounds__(512, 2) void qkv_gemm_8ph(const short* __restrict__ A,
                                                       const short* __restrict__ Bt,
                                                       const float* __restrict__ bias,
                                                       short* __restrict__ Yqk,
                                                       short* __restrict__ Yv) {
    __shared__ short Asl[32768];   // [2][256][64] bf16 = 64 KiB
    __shared__ short Bsl[32768];   // [2][256][64] bf16 = 64 KiB

    const int tid  = threadIdx.x;
    const int w    = tid >> 6;        // wave 0..7
    const int lane = tid & 63;
    const int l16  = lane & 15;
    const int quad = lane >> 4;
    const int wm   = w >> 2;          // 0..1 (M)
    const int wn   = w & 3;           // 0..3 (N)
    const int ls   = lane >> 3;       // staging: row-in-slot 0..7
    const int lc   = lane & 7;        // staging: chunk 0..7
    const int fsw  = l16 & 7;         // frag-read swizzle

    // XCD-aware bijective swizzle: XCD x gets an 8(M) x 3(N) tile patch
    const int orig = blockIdx.y * 12 + blockIdx.x;
    const int xcd  = orig & 7;
    const int idx  = orig >> 3;                      // 0..23
    const int bM   = ((xcd & 1) << 3) + (idx & 7);   // 0..15
    const int bN   = (xcd >> 1) * 3 + (idx >> 3);    // 0..11
    const int m0   = bM << 8;
    const int n0   = bN << 8;

    const short* Ab = A  + (size_t)m0 * K_GEMM;
    const short* Bb = Bt + (size_t)n0 * K_GEMM;

    f32x4 acc[8][4];
#pragma unroll
    for (int i = 0; i < 8; ++i)
#pragma unroll
        for (int j = 0; j < 4; ++j) acc[i][j] = (f32x4){0.f, 0.f, 0.f, 0.f};

    auto stageA = [&](int unit, int tt, int sbuf) {
#pragma unroll
        for (int i = 0; i < 2; ++i) {
            const int u0 = (i * 8 + w) * 8;                       // unit row base
            const int tr = (u0 & 63) + ((u0 >> 6) << 7) + unit * 64;
            gl2lds16(Ab + (size_t)(tr + ls) * K_GEMM + tt * 64 + ((lc ^ ls) << 3),
                     &Asl[sbuf * 16384 + tr * 64]);
        }
    };
    auto stageB = [&](int unit, int tt, int sbuf) {
#pragma unroll
        for (int i = 0; i < 2; ++i) {
            const int u0 = (i * 8 + w) * 8;
            const int tr = (u0 & 31) + ((u0 >> 5) << 6) + unit * 32;
            gl2lds16(Bb + (size_t)(tr + ls) * K_GEMM + tt * 64 + ((lc ^ ls) << 3),
                     &Bsl[sbuf * 16384 + tr * 64]);
        }
    };
    auto rdA = [&](int ab, int mi, int ks) -> short8 {
        const int r = wm * 128 + mi * 16 + l16;
        return *(const short8*)&Asl[ab + r * 64 + ((ks * 4 + quad) ^ fsw) * 8];
    };
    auto rdB = [&](int ab, int ni, int ks) -> short8 {
        const int r = wn * 64 + ni * 16 + l16;
        return *(const short8*)&Bsl[ab + r * 64 + ((ks * 4 + quad) ^ fsw) * 8];
    };

    // prologue: tile 0 -> buf 0, order AE,BE,BO,AO; keep BO,AO in flight.
    stageA(0, 0, 0);
    stageB(0, 0, 0);
    stageB(1, 0, 0);
    stageA(1, 0, 0);
    WAITV4();
    SCB();
    BARRIER();
    SCB();

    for (int t = 0; t < 16; ++t) {
        const int buf = t & 1;
        const int sb  = buf ^ 1;
        const int tn  = (t + 1) & 15;     // t==15 stages dummy tile 0 (uniform waits)
        const int ab  = buf * 16384;

        short8 Af[4][2], Bf[4][2];

        // ================= phase 0: quadrant (miH0 x niH0) ===================
#pragma unroll
        for (int mi = 0; mi < 4; ++mi)
#pragma unroll
            for (int ks = 0; ks < 2; ++ks) Af[mi][ks] = rdA(ab, mi, ks);
#pragma unroll
        for (int ni = 0; ni < 2; ++ni)
#pragma unroll
            for (int ks = 0; ks < 2; ++ks) Bf[ni][ks] = rdB(ab, ni, ks);
        stageA(0, tn, sb);
        SCB(); BARRIER(); LGKM0(); SCB();
        MFMA_QUAD(0, 0);
        WAITV4();
        SCB(); BARRIER(); SCB();

        // ================= phase 1: quadrant (miH0 x niH1) ===================
#pragma unroll
        for (int ni = 2; ni < 4; ++ni)
#pragma unroll
            for (int ks = 0; ks < 2; ++ks) Bf[ni][ks] = rdB(ab, ni, ks);
        stageB(0, tn, sb);
        SCB(); BARRIER(); LGKM0(); SCB();
        MFMA_QUAD(0, 2);
        WAITV4();
        SCB(); BARRIER(); SCB();

        // ===== phase 2: quadrant (miH1 x niH0); Bf[0..1] reused from regs ====
#pragma unroll
        for (int mi = 0; mi < 4; ++mi)
#pragma unroll
            for (int ks = 0; ks < 2; ++ks) Af[mi][ks] = rdA(ab, 4 + mi, ks);
        stageB(1, tn, sb);
        SCB(); BARRIER(); LGKM0(); SCB();
        MFMA_QUAD(4, 0);
        SCB(); BARRIER(); SCB();          // no vmcnt here

        // ===== phase 3: quadrant (miH1 x niH1); Af + Bf[2..3] from regs ======
        stageA(1, tn, sb);
        SCB(); BARRIER(); SCB();
        MFMA_QUAD(4, 2);
        WAITV4();
        SCB(); BARRIER(); SCB();
    }
    WAITV0();   // drain dummy loads: no LDS-DMA may outlive the workgroup

    // ---- epilogue ----
    if (n0 >= 2 * CDIM) {
        // V block: write transposed, 4 consecutive rows packed per 8B store
#pragma unroll
        for (int mi = 0; mi < 8; ++mi) {
            int row0 = m0 + wm * 128 + mi * 16 + quad * 4;
#pragma unroll
            for (int ni = 0; ni < 4; ++ni) {
                int colg = n0 + wn * 64 + ni * 16 + l16;
                float bb = bias[colg];
                short4v pk;
#pragma unroll
                for (int r = 0; r < 4; ++r) pk[r] = bf16_rn(acc[mi][ni][r] + bb);
                *(short4v*)&Yv[(size_t)(colg - 2 * CDIM) * M_GEMM + row0] = pk;
            }
        }
    } else {
        // Q pre-scale folds BOTH 1/sqrt(64) and log2(e): attn does p = 2^s
        const float qs = (n0 < CDIM) ? 0.125f * 1.44269504f : 1.0f;
#pragma unroll
        for (int mi = 0; mi < 8; ++mi)
#pragma unroll
            for (int r = 0; r < 4; ++r) {
                int row = m0 + wm * 128 + mi * 16 + quad * 4 + r;
#pragma unroll
                for (int ni = 0; ni < 4; ++ni) {
                    int colg = n0 + wn * 64 + ni * 16 + l16;
                    Yqk[(size_t)row * QK_PITCH + colg] =
                        bf16_rn((acc[mi][ni][r] + bias[colg]) * qs);
                }
            }
    }
}

// ---------- Kernel 2: causal flash attention, in-register P (R20) ------------
// R20: SWAPPED QK^T (S = mfma(K, Q)) with a quad-permuted K-row read so the
// score matrix lands DIRECTLY in the PV A-fragment layout. P never touches
// LDS: removes 16 ds_write_b16 + 8 ds_read_b128 per wave-tile (~40% of LDS
// traffic) and the softmax->PV lgkm chain (was the critical path: MfmaUtil
// 13%, VALU 32%, nothing saturated -> LDS-latency/throughput bound).
//  - A-read permutation: for block nt, lane l16 reads K row
//      F(nt,l16) = (nt>>1)*32 + (l16>>2)*8 + (nt&1)*4 + (l16&3)
//    => output (quad, reg r) holds key = (nt>>1)*32 + quad*8 + (nt&1)*4 + r,
//    i.e. lane l16 owns q-row l16 with keys {ks*32 + quad*8 + j} — exactly
//    the PV A-frag (k = ks*32 + quad*8 + j) after bf16 pack. Zero shuffles.
//  - Ks chunk-hash changed to hK(row) = (row&7) ^ (((row>>4)&1)<<2) ^
//    ((row>>3)&1): the permuted read varies row bits {0,1,3,4} and chunk-sel
//    bits {0,1}; hK injects row bits 3,4 into chunk bits 0,2 -> 8 uniform
//    chunks/instruction = minimal 8 touches/bank (verified by enumeration).
//    Staging and reads use the same hK (both-sides-or-neither). V unchanged.
//  - l_run is now a lane-scalar (q = l16); epilogue reduces xor16+xor32 and
//    redistributes via one shfl per r.  T5 setprio wraps both MFMA clusters.
__global__ __launch_bounds__(256) void attn_mfma(const short* __restrict__ qk,
                                                 const short* __restrict__ vT,
                                                 float* __restrict__ out) {
    const int b = blockIdx.z;
    const int h = blockIdx.y;
    const int bx = blockIdx.x;           // 0..31
    const int u = h + 16 * b;            // 0..31
    const int band = u >> 3;             // 0..3
    const int base = (band & 2) ? ((bx + 16) & 31) : bx;
    const int qt = (band & 1) ? (31 - base) : base;
    const int tid = threadIdx.x;
    const int w = tid >> 6;
    const int lane = tid & 63;
    const int quad = lane >> 4;
    const int l16 = lane & 15;
    const int q0 = qt * 64;

    __shared__ short Ks[2][64 * 64];     // [buf][key][d], hK-swizzled   16 KB
    __shared__ short Vt[2][64 * 64];     // [buf][d][key], row&7-swizzled 16 KB

    // staging descriptors: issue p covers chunks cid = p*256 + w*64 + lane
    int koff[2], voff[2], ldso[2];
#pragma unroll
    for (int p = 0; p < 2; ++p) {
        int cid = p * 256 + w * 64 + lane;
        int row = cid >> 3;
        int hK = (row & 7) ^ (((row >> 4) & 1) << 2) ^ ((row >> 3) & 1);
        int cK = (cid & 7) ^ hK;
        int cV = (cid & 7) ^ (row & 7);
        koff[p] = row * QK_PITCH + cK * 8;
        voff[p] = row * M_GEMM + cV * 8;
        ldso[p] = (p * 256 + w * 64) * 8;    // wave-uniform chunk base (shorts)
    }

    // Q fragments (B-layout for swapped QK^T: B[k=d][n=q], lane l16 = q)
    const short* qrow = qk + (size_t)(b * SEQ + q0 + w * 16 + l16) * QK_PITCH + h * HDIM;
    short8 aq[2];
    aq[0] = *(const short8*)(qrow + quad * 8);
    aq[1] = *(const short8*)(qrow + 32 + quad * 8);

    float l_run = 0.f;                   // lane-scalar: q-row = l16
    f32x4 o_acc[4];
#pragma unroll
    for (int dt = 0; dt < 4; ++dt) o_acc[dt] = (f32x4){0.f, 0.f, 0.f, 0.f};

    const int qglob = q0 + w * 16 + l16; // this lane's q row (for mask)
    const short* kb0 = qk + (size_t)(b * SEQ) * QK_PITCH + CDIM + h * HDIM;
    const short* vb0 = vT + (size_t)(h * HDIM) * M_GEMM + b * SEQ;

    const int ksl = l16 & 7;

    // permuted K-row per nt-block: F(nt,l16) and its hash (compile-time per nt)
    const int Fq = ((l16 >> 2) << 3) + (l16 & 3);   // quad-permuted base

    // prologue: stage tile 0 into buf 0
#pragma unroll
    for (int p = 0; p < 2; ++p) {
        gl2lds16(kb0 + koff[p], &Ks[0][ldso[p]]);
        gl2lds16(vb0 + voff[p], &Vt[0][ldso[p]]);
    }
    __syncthreads();                     // prologue staging drained

    for (int kt = 0; kt <= qt; ++kt) {
        const int cur = kt & 1;

        // prefetch tile kt+1 into the other buffer (overlaps compute)
        if (kt < qt) {
            const short* kbase = kb0 + (size_t)(kt + 1) * 64 * QK_PITCH;
            const short* vbase = vb0 + (kt + 1) * 64;
#pragma unroll
            for (int p = 0; p < 2; ++p) {
                gl2lds16(kbase + koff[p], &Ks[cur ^ 1][ldso[p]]);
                gl2lds16(vbase + voff[p], &Vt[cur ^ 1][ldso[p]]);
            }
        }

        const short* KsC = Ks[cur];
        const short* VtC = Vt[cur];

        // ---- swapped QK^T: s[nt][r] = S[key][q=l16], key per-lane mapped ----
        f32x4 s[4];
#pragma unroll
        for (int nt = 0; nt < 4; ++nt) s[nt] = (f32x4){0.f, 0.f, 0.f, 0.f};
        __builtin_amdgcn_s_setprio(1);
#pragma unroll
        for (int nt = 0; nt < 4; ++nt) {
            const int F  = (nt >> 1) * 32 + (nt & 1) * 4 + Fq;
            const int hF = (F & 7) ^ (((F >> 4) & 1) << 2) ^ ((F >> 3) & 1);
#pragma unroll
            for (int ks = 0; ks < 2; ++ks) {
                short8 kf = *(const short8*)&KsC[F * 64 + (((ks * 4 + quad) ^ hF) * 8)];
                s[nt] = __builtin_amdgcn_mfma_f32_16x16x32_bf16(kf, aq[ks], s[nt], 0, 0, 0);
            }
        }
        __builtin_amdgcn_s_setprio(0);

        // ---- softmax in registers: p = 2^s, pack straight into PV A-frags --
        short8 pa0, pa1;
        float lsum = 0.f;
        if (kt < qt) {                   // full tile
#pragma unroll
            for (int nt = 0; nt < 4; ++nt)
#pragma unroll
                for (int r = 0; r < 4; ++r) {
                    float pp = __builtin_amdgcn_exp2f(s[nt][r]);
                    lsum += pp;
                    short pb = bf16_rn(pp);
                    if (nt < 2) pa0[(nt & 1) * 4 + r] = pb;
                    else        pa1[(nt & 1) * 4 + r] = pb;
                }
        } else {                         // diagonal tile: causal mask
#pragma unroll
            for (int nt = 0; nt < 4; ++nt)
#pragma unroll
                for (int r = 0; r < 4; ++r) {
                    int key = kt * 64 + (nt >> 1) * 32 + quad * 8 + (nt & 1) * 4 + r;
                    float pp = __builtin_amdgcn_exp2f(s[nt][r]);
                    pp = (key > qglob) ? 0.f : pp;
                    lsum += pp;
                    short pb = bf16_rn(pp);
                    if (nt < 2) pa0[(nt & 1) * 4 + r] = pb;
                    else        pa1[(nt & 1) * 4 + r] = pb;
                }
        }
        l_run += lsum;

        // ---- PV: O[16 q][64 d] += P @ V; P is already the A-fragment ------
        __builtin_amdgcn_s_setprio(1);
#pragma unroll
        for (int dt = 0; dt < 4; ++dt)
#pragma unroll
            for (int ks = 0; ks < 2; ++ks) {
                short8 bv = *(const short8*)&VtC[(dt * 16 + l16) * 64 +
                                                 ((ks * 4 + quad) ^ ksl) * 8];
                o_acc[dt] = __builtin_amdgcn_mfma_f32_16x16x32_bf16(
                    ks ? pa1 : pa0, bv, o_acc[dt], 0, 0, 0);
            }
        __builtin_amdgcn_s_setprio(0);

        // one barrier/tile: drains prefetch + guards buffer reuse
        __syncthreads();
    }

    // ---- epilogue: l lives at q=l16 (partial over quads) -> reduce, redist -
    float l = l_run;
    l += __shfl_xor(l, 16);
    l += __shfl_xor(l, 32);              // now full row-sum for q=l16, all quads
#pragma unroll
    for (int r = 0; r < 4; ++r) {
        float lq = __shfl(l, quad * 4 + r);   // sum for q-row quad*4+r
        float inv = 1.f / lq;
        int row = q0 + w * 16 + quad * 4 + r;
        float* optr = out + (size_t)(b * SEQ + row) * CDIM + h * HDIM;
#pragma unroll
        for (int dt = 0; dt < 4; ++dt)
            optr[dt * 16 + l16] = o_acc[dt][r] * inv;
    }
}

// ------------------------------- launch --------------------------------------
extern "C" void kernel_launch(void* const* d_in, const int* in_sizes, int n_in,
                              void* d_out, int out_size, void* d_ws, size_t ws_size,
                              hipStream_t stream) {
    const float* x      = (const float*)d_in[0];   // [B,T,C] fp32
    const float* w_attn = (const float*)d_in[1];   // [C,3C]  fp32
    const float* b_attn = (const float*)d_in[2];   // [3C]    fp32
    float* out = (float*)d_out;                    // [B,T,C] fp32

    // workspace: qk [4096][2048] 16.78MB | vT [1024][4096] 8.39MB | xb 8.39MB | wT 6.29MB
    short* qk  = (short*)d_ws;
    short* vT  = (short*)((char*)d_ws + 16777216);
    short* xb  = (short*)((char*)d_ws + 25165824);
    short* wT  = (short*)((char*)d_ws + 33554432);

    cvt_fused<<<2048 + 768, 256, 0, stream>>>(x, w_attn, xb, wT);

    dim3 g1(N_GEMM / 256, M_GEMM / 256);                                // (12,16)
    qkv_gemm_8ph<<<g1, 512, 0, stream>>>(xb, wT, b_attn, qk, vT);

    dim3 g2(SEQ / 64, NHEAD, BSZ);                                      // (32,16,2)
    attn_mfma<<<g2, 256, 0, stream>>>(qk, vT, out);
}